// Round 3
// baseline (313.072 us; speedup 1.0000x reference)
//
#include <hip/hip_runtime.h>
#include <hip/hip_bf16.h>

typedef short s8v __attribute__((ext_vector_type(8)));
typedef short s4v __attribute__((ext_vector_type(4)));
typedef float f4v __attribute__((ext_vector_type(4)));

#define DEV __device__ __forceinline__

DEV unsigned short f2b(float f) {
  unsigned u = __builtin_bit_cast(unsigned, f);
  u += 0x7FFFu + ((u >> 16) & 1u);
  return (unsigned short)(u >> 16);
}
DEV float b2f(unsigned short s) {
  unsigned u = ((unsigned)s) << 16;
  return __builtin_bit_cast(float, u);
}

// ---------------- workspace layout (bytes, all 256-aligned) ----------------
#define O_WHH0  0u          // 131072  bf16 frag-packed whh0
#define O_WHH1  131072u     // 131072
#define O_WIH0  262144u     // 65536
#define O_WIH1  327680u     // 131072
#define O_B0    458752u     // 2048    f32 permuted bih0+bhh0
#define O_B1    460800u     // 2048
#define O_WA    462848u     // 8192    f32 folded comb_w[:, :64] @ de_w2  (64x32)
#define O_EMB2  471040u     // 4096    f32 embed @ comb_w[:,64:80]^T     (16x64)
#define O_BC    475136u     // 256     f32 comb_b + comb_w[:,:64]@de_b2  (64)
#define O_DP1T  475392u     // 32768   bf16 dp_w1 [d][k^((d&15)<<3)] 128x128
#define O_CP1T  508160u     // 16384   bf16 cp_w1 [d][k^..] 64x128
#define O_PC1T  524544u     // 8192    bf16 pc_w1 [d][k^..] 32x128
#define O_DP2T  532736u     // 4096    f32 dp_w2^T [k][o] 128x8
#define O_CP2T  536832u     // 2048    f32 cp_w2^T 64x8
#define O_PC2T  538880u     // 512     f32 pc_w2^T 32x4
#define O_FEATS 4733696u    // 33554432 bf16 feats [b*32+t][64] natural
#define O_Y0    38288128u   // 67108864 bf16 y0    [blk][t][row32][128]

// LDS pool offsets (bytes)
#define P_H0   0
#define P_H1   8192
#define P_HF   16384      // f32 [32][128] final h
#define P_W1   32768      // bf16 head w1: dp(16384) cp(8192) pc(4096) shorts
#define P_W2   90112      // f32 1664
#define P_B1   96768      // f32 224
#define P_MID  97664      // f32 7168
#define P_PC   126336     // f32 128
#define P_TOT  126976

// Column permutation: reordered col c (0..511) -> orig gate-major row of W.
DEV int orig_col(int c) { return 128 * ((c >> 4) & 3) + 16 * (c >> 6) + (c & 15); }

// =============================== prep ===============================
__global__ void prep_kernel(
    const float* de_w1, const float* de_b1, const float* de_w2, const float* de_b2,
    const float* embed, const float* comb_w, const float* comb_b,
    const float* w0ih, const float* w0hh, const float* b0ih, const float* b0hh,
    const float* w1ih, const float* w1hh, const float* b1ih, const float* b1hh,
    const float* dp_w1, const float* dp_w2, const float* cp_w1, const float* cp_w2,
    const float* pc_w1, const float* pc_w2, char* ws)
{
  unsigned short* wih0p = (unsigned short*)(ws + O_WIH0);
  unsigned short* whh0p = (unsigned short*)(ws + O_WHH0);
  unsigned short* wih1p = (unsigned short*)(ws + O_WIH1);
  unsigned short* whh1p = (unsigned short*)(ws + O_WHH1);
  float* b0p = (float*)(ws + O_B0);
  float* b1p = (float*)(ws + O_B1);
  float* Wa  = (float*)(ws + O_WA);
  float* bc  = (float*)(ws + O_BC);
  float* em2 = (float*)(ws + O_EMB2);
  unsigned short* dp1t = (unsigned short*)(ws + O_DP1T);
  unsigned short* cp1t = (unsigned short*)(ws + O_CP1T);
  unsigned short* pc1t = (unsigned short*)(ws + O_PC1T);
  float* dp2t = (float*)(ws + O_DP2T);
  float* cp2t = (float*)(ws + O_CP2T);
  float* pc2t = (float*)(ws + O_PC2T);

  const int T0 = 32768, T1 = T0 + 65536, T2 = T1 + 65536, T3 = T2 + 65536,
            T4 = T3 + 512, T5 = T4 + 512, T6 = T5 + 2048, T7 = T6 + 64,
            T8 = T7 + 1024, T9 = T8 + 16384, T10 = T9 + 8192, T11 = T10 + 4096,
            T12 = T11 + 1024, T13 = T12 + 512, T14 = T13 + 128;

  for (int idx = blockIdx.x * 256 + threadIdx.x; idx < T14; idx += gridDim.x * 256) {
    if (idx < T3) {  // MFMA fragment packing
      int u, Kin; const float* src; unsigned short* dst;
      if (idx < T0)      { u = idx;      Kin = 64;  src = w0ih; dst = wih0p; }
      else if (idx < T1) { u = idx - T0; Kin = 128; src = w0hh; dst = whh0p; }
      else if (idx < T2) { u = idx - T1; Kin = 128; src = w1ih; dst = wih1p; }
      else               { u = idx - T2; Kin = 128; src = w1hh; dst = whh1p; }
      int j = u & 7, l = (u >> 3) & 63, nt = (u >> 9) & 31, kt = u >> 14;
      int c = 16 * nt + (l & 15);
      int k = 32 * kt + 8 * (l >> 4) + j;
      dst[u] = f2b(src[orig_col(c) * Kin + k]);
    } else if (idx < T5) {  // permuted biases
      int u = idx - T3;
      if (u < 512) b0p[u] = b0ih[orig_col(u)] + b0hh[orig_col(u)];
      else { int c = u - 512; b1p[c] = b1ih[orig_col(c)] + b1hh[orig_col(c)]; }
    } else if (idx < T6) {  // W_a[f][kk]
      int u = idx - T5, f = u >> 5, kk = u & 31;
      float a = 0.f;
      for (int f2 = 0; f2 < 64; f2++) a += comb_w[f * 80 + f2] * de_w2[f2 * 32 + kk];
      Wa[u] = a;
    } else if (idx < T7) {  // b_comb
      int f = idx - T6;
      float a = comb_b[f];
      for (int f2 = 0; f2 < 64; f2++) a += comb_w[f * 80 + f2] * de_b2[f2];
      bc[f] = a;
    } else if (idx < T8) {  // emb2[e][f]
      int u = idx - T7, e = u >> 6, f = u & 63;
      float a = 0.f;
      for (int j = 0; j < 16; j++) a += embed[e * 16 + j] * comb_w[f * 80 + 64 + j];
      em2[u] = a;
    } else if (idx < T9)  { int u = idx - T8;  int dd = u >> 7, kx = u & 127; dp1t[u] = f2b(dp_w1[dd * 128 + (kx ^ ((dd & 15) << 3))]); }
    else if (idx < T10)   { int u = idx - T9;  int dd = u >> 7, kx = u & 127; cp1t[u] = f2b(cp_w1[dd * 128 + (kx ^ ((dd & 15) << 3))]); }
    else if (idx < T11)   { int u = idx - T10; int dd = u >> 7, kx = u & 127; pc1t[u] = f2b(pc_w1[dd * 128 + (kx ^ ((dd & 15) << 3))]); }
    else if (idx < T12)   { int u = idx - T11; int k = u >> 3, o = u & 7;   dp2t[u] = dp_w2[o * 128 + k]; }
    else if (idx < T13)   { int u = idx - T12; int k = u >> 3, o = u & 7;   cp2t[u] = cp_w2[o * 64 + k]; }
    else                  { int u = idx - T13; int k = u >> 2, o = u & 3;   pc2t[u] = pc_w2[o * 32 + k]; }
  }
}

// =============================== frontend ===============================
__global__ __launch_bounds__(256) void frontend_kernel(
    const float* __restrict__ x_feat, const int* __restrict__ acc_t,
    const float* __restrict__ de_w1, const float* __restrict__ de_b1,
    const char* __restrict__ ws, unsigned short* __restrict__ feats)
{
  __shared__ float sW1[256], sB1[32], sWa[2048], sBc[64], sE2T[1024];
  const float* Wa  = (const float*)(ws + O_WA);
  const float* bc  = (const float*)(ws + O_BC);
  const float* em2 = (const float*)(ws + O_EMB2);
  int tid = threadIdx.x;
  sW1[tid] = de_w1[tid];
  if (tid < 32) sB1[tid] = de_b1[tid];
  for (int i = tid; i < 2048; i += 256) sWa[i] = Wa[i];
  if (tid < 64) sBc[tid] = bc[tid];
  for (int i = tid; i < 1024; i += 256) sE2T[i] = em2[(i & 15) * 64 + (i >> 4)];
  __syncthreads();

  int g = blockIdx.x * 256 + tid;  // g = b*32 + t
  f4v x0 = ((const f4v*)(x_feat + (size_t)g * 8))[0];
  f4v x1 = ((const f4v*)(x_feat + (size_t)g * 8))[1];
  float xs[8];
#pragma unroll
  for (int i = 0; i < 4; i++) { xs[i] = x0[i]; xs[4 + i] = x1[i]; }
  int at = acc_t[g];

  float r1[32];
#pragma unroll
  for (int kk = 0; kk < 32; kk++) {
    float a = sB1[kk];
#pragma unroll
    for (int i = 0; i < 8; i++) a += xs[i] * sW1[kk * 8 + i];
    r1[kk] = fmaxf(a, 0.f);
  }
  unsigned short* dst = feats + (size_t)g * 64;
  for (int j8 = 0; j8 < 8; j8++) {
    s8v pack;
#pragma unroll
    for (int jj = 0; jj < 8; jj++) {
      int j = j8 * 8 + jj;
      float a = sBc[j] + sE2T[j * 16 + at];
      const f4v* wr = (const f4v*)(sWa + j * 32);
#pragma unroll
      for (int k4 = 0; k4 < 8; k4++) {
        f4v wv = wr[k4];
        a += r1[4 * k4 + 0] * wv[0] + r1[4 * k4 + 1] * wv[1] +
             r1[4 * k4 + 2] * wv[2] + r1[4 * k4 + 3] * wv[3];
      }
      pack[jj] = (short)f2b(a);
    }
    *(s8v*)(dst + j8 * 8) = pack;
  }
}

// =============================== heads (block-local epilogue) ===============================
DEV void heads_phase(int tid, int blk, char* pool,
                     const float* __restrict__ dp_b2, const float* __restrict__ cp_b2,
                     const float* __restrict__ pc_b2, float* __restrict__ out)
{
  const float* sh = (const float*)(pool + P_HF);
  const unsigned short* sw1 = (const unsigned short*)(pool + P_W1);
  const float* sw2 = (const float*)(pool + P_W2);
  const float* sb1 = (const float*)(pool + P_B1);
  float* smid = (float*)(pool + P_MID);
  float* spc = (float*)(pool + P_PC);

  for (int i = tid; i < 7168; i += 512) {
    int row = i / 224, md = i - row * 224;
    const unsigned short* wr; int dd;
    if (md < 128)      { dd = md;       wr = sw1 + dd * 128; }
    else if (md < 192) { dd = md - 128; wr = sw1 + 16384 + dd * 128; }
    else               { dd = md - 192; wr = sw1 + 24576 + dd * 128; }
    float a = sb1[md];
    int s = (dd & 15) << 3;
    const float* hr = sh + row * 128;
#pragma unroll
    for (int kb = 0; kb < 16; kb++) {
      int k0 = (kb * 8) ^ s;
      s8v wv = *(const s8v*)(wr + kb * 8);
      f4v h0 = *(const f4v*)(hr + k0);
      f4v h1 = *(const f4v*)(hr + k0 + 4);
      a += h0[0] * b2f(wv[0]) + h0[1] * b2f(wv[1]) + h0[2] * b2f(wv[2]) + h0[3] * b2f(wv[3]) +
           h1[0] * b2f(wv[4]) + h1[1] * b2f(wv[5]) + h1[2] * b2f(wv[6]) + h1[3] * b2f(wv[7]);
    }
    smid[i] = fmaxf(a, 0.f);
  }
  __syncthreads();

  for (int i = tid; i < 640; i += 512) {
    int row = i / 20, o = i - row * 20;
    if (o < 8) {
      float a = dp_b2[o];
      for (int k = 0; k < 128; k++) a += smid[row * 224 + k] * sw2[k * 8 + o];
      out[(size_t)(blk * 32 + row) * 20 + o] = a * 1e6f;
    } else if (o < 16) {
      int oo = o - 8; float a = cp_b2[oo];
      for (int k = 0; k < 64; k++) a += smid[row * 224 + 128 + k] * sw2[1024 + k * 8 + oo];
      out[(size_t)(blk * 32 + row) * 20 + o] =
          __builtin_amdgcn_rcpf(1.f + __expf(-a));
    } else {
      int oo = o - 16; float a = pc_b2[oo];
      for (int k = 0; k < 32; k++) a += smid[row * 224 + 192 + k] * sw2[1536 + k * 4 + oo];
      spc[row * 4 + oo] = a;
    }
  }
  __syncthreads();

  if (tid < 32) {
    int row = tid;
    float v0 = spc[row * 4], v1 = spc[row * 4 + 1], v2 = spc[row * 4 + 2], v3 = spc[row * 4 + 3];
    float m = fmaxf(fmaxf(v0, v1), fmaxf(v2, v3));
    float e0 = __expf(v0 - m), e1 = __expf(v1 - m), e2 = __expf(v2 - m), e3 = __expf(v3 - m);
    float rs = __builtin_amdgcn_rcpf(e0 + e1 + e2 + e3);
    size_t base = (size_t)(blk * 32 + row) * 20 + 16;
    out[base] = e0 * rs; out[base + 1] = e1 * rs; out[base + 2] = e2 * rs; out[base + 3] = e3 * rs;
  }
}

// =============================== main LSTM ===============================
template <int PASS>
DEV void run_pass(int tid, int blk,
                  const unsigned short* __restrict__ whhp,
                  const unsigned short* __restrict__ wihp,
                  const float* __restrict__ bp,
                  const unsigned short* __restrict__ inglob,
                  unsigned short* __restrict__ y0buf,
                  char* pool)
{
  constexpr int NKT = PASS ? 4 : 2;
  constexpr int STEPB = PASS ? 8192 : 128;   // byte stride of input per t
  const int w = tid >> 6, l = tid & 63, l15 = l & 15, lhi = l >> 4;
  const int d = 16 * w + l15;
  const char* gb = (const char*)inglob;

  // per-lane A-load base pointers at t=0 (even bank) / t=1 (odd bank), per mt
  const char *pe0, *pe1, *po0, *po1;
  {
    int row0 = l15, row1 = 16 + l15;
    if constexpr (PASS == 0) {
      pe0 = gb + (size_t)(blk * 32 + row0) * 4096 + lhi * 16;
      pe1 = gb + (size_t)(blk * 32 + row1) * 4096 + lhi * 16;
    } else {
      pe0 = gb + (size_t)blk * 262144 + row0 * 256 + lhi * 16;
      pe1 = gb + (size_t)blk * 262144 + row1 * 256 + lhi * 16;
    }
    po0 = pe0 + STEPB; po1 = pe1 + STEPB;
  }

  // weights -> registers (per-wave slices of pre-packed fragments)
  s8v wf[NKT][4], bfr[4][4];
#pragma unroll
  for (int kt = 0; kt < NKT; kt++)
#pragma unroll
    for (int gg = 0; gg < 4; gg++)
      wf[kt][gg] = *(const s8v*)(wihp + ((size_t)(kt * 32 + 4 * w + gg) * 64 + l) * 8);
#pragma unroll
  for (int kt = 0; kt < 4; kt++)
#pragma unroll
    for (int gg = 0; gg < 4; gg++)
      bfr[kt][gg] = *(const s8v*)(whhp + ((size_t)(kt * 32 + 4 * w + gg) * 64 + l) * 8);

  // biases folded into activation args
  const float nbi = -bp[64 * w + l15],      nbf = -bp[64 * w + 16 + l15],
              bg2 = 2.f * bp[64 * w + 32 + l15], nbo = -bp[64 * w + 48 + l15];

  // invariant LDS h-read addresses
  int hra[2][4];
#pragma unroll
  for (int mt = 0; mt < 2; mt++)
#pragma unroll
    for (int kt = 0; kt < 4; kt++) {
      int row = 16 * mt + l15;
      hra[mt][kt] = row * 256 + ((kt * 64 + lhi * 16) ^ ((row & 7) << 4));
    }

  float cst[2][4] = {{0, 0, 0, 0}, {0, 0, 0, 0}};

  const int yldsb = (tid >> 4) * 256 + (tid & 15) * 16;
  unsigned short* py0 = nullptr;
  if constexpr (PASS == 0)
    py0 = y0buf + (size_t)blk * 131072 + (tid >> 4) * 128 +
          (((tid & 15) ^ ((tid >> 4) & 7)) * 8);

  // zero h buffer 0
  { s8v z = {0, 0, 0, 0, 0, 0, 0, 0}; *(s8v*)((unsigned short*)(pool + P_H0) + tid * 8) = z; }

  // prologue: A(0) -> AA, acc = input(0); issue A(1) -> AB
  s8v AA[2][NKT], AB[2][NKT];
#pragma unroll
  for (int kt = 0; kt < NKT; kt++) {
    AA[0][kt] = *(const s8v*)(pe0 + kt * 64);
    AA[1][kt] = *(const s8v*)(pe1 + kt * 64);
  }
  pe0 += 2 * STEPB; pe1 += 2 * STEPB;

  f4v acc[2][4];
  const f4v z4 = {0.f, 0.f, 0.f, 0.f};
#pragma unroll
  for (int mt = 0; mt < 2; mt++)
#pragma unroll
    for (int gg = 0; gg < 4; gg++)
      acc[mt][gg] = __builtin_amdgcn_mfma_f32_16x16x32_bf16(AA[mt][0], wf[0][gg], z4, 0, 0, 0);
#pragma unroll
  for (int kt = 1; kt < NKT; kt++)
#pragma unroll
    for (int mt = 0; mt < 2; mt++)
#pragma unroll
      for (int gg = 0; gg < 4; gg++)
        acc[mt][gg] = __builtin_amdgcn_mfma_f32_16x16x32_bf16(AA[mt][kt], wf[kt][gg], acc[mt][gg], 0, 0, 0);

#pragma unroll
  for (int kt = 0; kt < NKT; kt++) {
    AB[0][kt] = *(const s8v*)(po0 + kt * 64);
    AB[1][kt] = *(const s8v*)(po1 + kt * 64);
  }
  po0 += 2 * STEPB; po1 += 2 * STEPB;

#define HSTEP(T, HRDOFF, HWROFF, PRE0, PRE1, PREB, CONSB)                        \
  {                                                                              \
    __syncthreads();                                                             \
    if ((T) < 30) {                                                              \
      _Pragma("unroll") for (int kt = 0; kt < NKT; kt++) {                       \
        PREB[0][kt] = *(const s8v*)(PRE0 + kt * 64);                             \
        PREB[1][kt] = *(const s8v*)(PRE1 + kt * 64);                             \
      }                                                                          \
      PRE0 += 2 * STEPB; PRE1 += 2 * STEPB;                                      \
    }                                                                            \
    const char* hrd = pool + (HRDOFF);                                           \
    _Pragma("unroll") for (int kt = 0; kt < 4; kt++)                             \
      _Pragma("unroll") for (int mt = 0; mt < 2; mt++) {                         \
        s8v ha = *(const s8v*)(hrd + hra[mt][kt]);                               \
        _Pragma("unroll") for (int gg = 0; gg < 4; gg++)                         \
          acc[mt][gg] = __builtin_amdgcn_mfma_f32_16x16x32_bf16(                 \
              ha, bfr[kt][gg], acc[mt][gg], 0, 0, 0);                            \
      }                                                                          \
    if (PASS == 0 && (T) > 0) {                                                  \
      s8v hv8 = *(const s8v*)(hrd + yldsb);                                      \
      *(s8v*)py0 = hv8; py0 += 4096;                                             \
    }                                                                            \
    _Pragma("unroll") for (int mt = 0; mt < 2; mt++)                             \
      _Pragma("unroll") for (int r = 0; r < 4; r++) {                            \
        float xi = acc[mt][0][r], xf = acc[mt][1][r],                            \
              xg = acc[mt][2][r], xo = acc[mt][3][r];                            \
        float iv = __builtin_amdgcn_rcpf(1.f + __expf(fmaf(xi, -1.f, nbi)));     \
        float fv = __builtin_amdgcn_rcpf(1.f + __expf(fmaf(xf, -1.f, nbf)));     \
        float ov = __builtin_amdgcn_rcpf(1.f + __expf(fmaf(xo, -1.f, nbo)));     \
        float eg = __expf(fmaf(xg, 2.f, bg2));                                   \
        float gv = fmaf(-2.f, __builtin_amdgcn_rcpf(eg + 1.f), 1.f);             \
        float cv = fmaf(fv, cst[mt][r], iv * gv);                                \
        cst[mt][r] = cv;                                                         \
        float ec = __expf(2.f * cv);                                             \
        float th = fmaf(-2.f, __builtin_amdgcn_rcpf(ec + 1.f), 1.f);             \
        float hv = ov * th;                                                      \
        int row = 16 * mt + 4 * lhi + r;                                         \
        if (PASS == 1 && (T) == 31) {                                            \
          ((float*)(pool + P_HF))[row * 128 + d] = hv;                           \
        } else {                                                                 \
          *(unsigned short*)(pool + (HWROFF) + row * 256 +                       \
                             ((d * 2) ^ ((row & 7) << 4))) = f2b(hv);            \
        }                                                                        \
      }                                                                          \
    if ((T) < 31) {                                                              \
      _Pragma("unroll") for (int mt = 0; mt < 2; mt++)                           \
        _Pragma("unroll") for (int gg = 0; gg < 4; gg++)                         \
          acc[mt][gg] = __builtin_amdgcn_mfma_f32_16x16x32_bf16(                 \
              CONSB[mt][0], wf[0][gg], z4, 0, 0, 0);                             \
      _Pragma("unroll") for (int kt = 1; kt < NKT; kt++)                         \
        _Pragma("unroll") for (int mt = 0; mt < 2; mt++)                         \
          _Pragma("unroll") for (int gg = 0; gg < 4; gg++)                       \
            acc[mt][gg] = __builtin_amdgcn_mfma_f32_16x16x32_bf16(               \
                CONSB[mt][kt], wf[kt][gg], acc[mt][gg], 0, 0, 0);                \
    }                                                                            \
  }

  for (int th = 0; th < 16; ++th) {
    int Ta = 2 * th, Tb = 2 * th + 1;
    HSTEP(Ta, P_H0, P_H1, pe0, pe1, AA, AB)
    HSTEP(Tb, P_H1, P_H0, po0, po1, AB, AA)
  }
#undef HSTEP

  if constexpr (PASS == 0) {  // h(31) is in buffer 0
    __syncthreads();
    s8v hv8 = *(const s8v*)(pool + P_H0 + yldsb);
    *(s8v*)py0 = hv8;
  }
}

__global__ __launch_bounds__(512, 2) void lstm_main(
    const char* __restrict__ ws_c, char* __restrict__ ws,
    const float* __restrict__ dp_b1, const float* __restrict__ dp_b2,
    const float* __restrict__ cp_b1, const float* __restrict__ cp_b2,
    const float* __restrict__ pc_b1, const float* __restrict__ pc_b2,
    float* __restrict__ out)
{
  __shared__ __align__(16) char pool[P_TOT];
  int tid = threadIdx.x, blk = blockIdx.x;

  // one-time head-weight staging (regions untouched by passes; ordered by later barriers)
  {
    const s8v* w1s = (const s8v*)(ws_c + O_DP1T);  // dp1|cp1|pc1 contiguous: 3584 s8v
    s8v* dstw = (s8v*)(pool + P_W1);
    for (int i = tid; i < 3584; i += 512) dstw[i] = w1s[i];
    const float* w2s = (const float*)(ws_c + O_DP2T);  // dp2|cp2|pc2 contiguous: 1664 f32
    float* d2 = (float*)(pool + P_W2);
    for (int i = tid; i < 1664; i += 512) d2[i] = w2s[i];
    float* b1 = (float*)(pool + P_B1);
    if (tid < 128) b1[tid] = dp_b1[tid];
    else if (tid < 192) b1[tid] = cp_b1[tid - 128];
    else if (tid < 224) b1[tid] = pc_b1[tid - 192];
  }

  run_pass<0>(tid, blk,
              (const unsigned short*)(ws_c + O_WHH0), (const unsigned short*)(ws_c + O_WIH0),
              (const float*)(ws_c + O_B0),
              (const unsigned short*)(ws_c + O_FEATS),
              (unsigned short*)(ws + O_Y0), pool);
  __syncthreads();
  run_pass<1>(tid, blk,
              (const unsigned short*)(ws_c + O_WHH1), (const unsigned short*)(ws_c + O_WIH1),
              (const float*)(ws_c + O_B1),
              (const unsigned short*)(ws + O_Y0),
              nullptr, pool);
  __syncthreads();
  heads_phase(tid, blk, pool, dp_b2, cp_b2, pc_b2, out);
}

// =============================== launch ===============================
extern "C" void kernel_launch(void* const* d_in, const int* in_sizes, int n_in,
                              void* d_out, int out_size, void* d_ws, size_t ws_size,
                              hipStream_t stream) {
  const float* x_feat = (const float*)d_in[0];
  const int*   acc_t  = (const int*)d_in[1];
  const float* de_w1 = (const float*)d_in[2],  *de_b1 = (const float*)d_in[3];
  const float* de_w2 = (const float*)d_in[4],  *de_b2 = (const float*)d_in[5];
  const float* embed = (const float*)d_in[6];
  const float* comb_w = (const float*)d_in[7], *comb_b = (const float*)d_in[8];
  const float* w0ih = (const float*)d_in[9],  *w0hh = (const float*)d_in[10];
  const float* b0ih = (const float*)d_in[11], *b0hh = (const float*)d_in[12];
  const float* w1ih = (const float*)d_in[13], *w1hh = (const float*)d_in[14];
  const float* b1ih = (const float*)d_in[15], *b1hh = (const float*)d_in[16];
  const float* dp_w1 = (const float*)d_in[17], *dp_b1 = (const float*)d_in[18];
  const float* dp_w2 = (const float*)d_in[19], *dp_b2 = (const float*)d_in[20];
  const float* cp_w1 = (const float*)d_in[21], *cp_b1 = (const float*)d_in[22];
  const float* cp_w2 = (const float*)d_in[23], *cp_b2 = (const float*)d_in[24];
  const float* pc_w1 = (const float*)d_in[25], *pc_b1 = (const float*)d_in[26];
  const float* pc_w2 = (const float*)d_in[27], *pc_b2 = (const float*)d_in[28];
  char* ws = (char*)d_ws;

  prep_kernel<<<256, 256, 0, stream>>>(
      de_w1, de_b1, de_w2, de_b2, embed, comb_w, comb_b,
      w0ih, w0hh, b0ih, b0hh, w1ih, w1hh, b1ih, b1hh,
      dp_w1, dp_w2, cp_w1, cp_w2, pc_w1, pc_w2, ws);

  frontend_kernel<<<1024, 256, 0, stream>>>(
      x_feat, acc_t, de_w1, de_b1, ws, (unsigned short*)(ws + O_FEATS));

  lstm_main<<<256, 512, 0, stream>>>(
      ws, ws, dp_b1, dp_b2, cp_b1, cp_b2, pc_b1, pc_b2, (float*)d_out);
}

// Round 4
// 268.468 us; speedup vs baseline: 1.1661x; 1.1661x over previous
//
#include <hip/hip_runtime.h>
#include <hip/hip_bf16.h>

typedef short s8v __attribute__((ext_vector_type(8)));
typedef float f4v __attribute__((ext_vector_type(4)));

#define DEV __device__ __forceinline__

DEV unsigned short f2b(float f) {
  unsigned u = __builtin_bit_cast(unsigned, f);
  u += 0x7FFFu + ((u >> 16) & 1u);
  return (unsigned short)(u >> 16);
}
DEV float b2f(unsigned short s) {
  unsigned u = ((unsigned)s) << 16;
  return __builtin_bit_cast(float, u);
}

// ---------------- workspace layout (bytes, all 256-aligned) ----------------
#define O_WHH0  0u          // 131072  bf16 frag-packed whh0 (kt-major: kt*32768B)
#define O_WHH1  131072u     // 131072
#define O_WIH0  262144u     // 65536
#define O_WIH1  327680u     // 131072
#define O_B0    458752u     // 2048    f32 permuted bih0+bhh0
#define O_B1    460800u     // 2048
#define O_WA    462848u     // 8192
#define O_EMB2  471040u     // 4096
#define O_BC    475136u     // 256
#define O_DP1T  475392u     // 32768   bf16 dp_w1 [d][k^((d&15)<<3)]
#define O_CP1T  508160u     // 16384
#define O_PC1T  524544u     // 8192
#define O_DP2T  532736u     // 4096    f32 (dp2|cp2|pc2 contiguous 6656B)
#define O_CP2T  536832u
#define O_PC2T  538880u
#define O_FEATS 4733696u    // 33554432 bf16 feats [b*32+t][64]
#define O_Y0    38288128u   // 67108864 bf16 y0 [blk][t][row32][128]

// ---------------- LDS pool (131136 B) ----------------
// During passes:
#define P_H0    0        // 8192   h dbuf 0
#define P_H1    8192     // 8192   h dbuf 1
#define P_WLDS  16384    // 98304  whh kt0..2 B-frags (linear copy)
#define P_HF    114688   // 16384  f32 h_final[32][128]
#define P_CTR   131072   // 4
#define P_TOT   131136
// Heads phase (aliases 0..114688, after barrier):
#define P_HW1   0        // 57344  bf16 head w1 (dp|cp|pc)
#define P_HW2   57344    // 6656   f32 w2
#define P_HB1   64256    // 896    f32 b1
#define P_HMID  65536    // 28672  f32 mid
#define P_HPC   94720    // 512    f32 pre-softmax

DEV int orig_col(int c) { return 128 * ((c >> 4) & 3) + 16 * (c >> 6) + (c & 15); }

// =============================== prep ===============================
__global__ void prep_kernel(
    const float* de_w1, const float* de_b1, const float* de_w2, const float* de_b2,
    const float* embed, const float* comb_w, const float* comb_b,
    const float* w0ih, const float* w0hh, const float* b0ih, const float* b0hh,
    const float* w1ih, const float* w1hh, const float* b1ih, const float* b1hh,
    const float* dp_w1, const float* dp_w2, const float* cp_w1, const float* cp_w2,
    const float* pc_w1, const float* pc_w2, char* ws)
{
  unsigned short* wih0p = (unsigned short*)(ws + O_WIH0);
  unsigned short* whh0p = (unsigned short*)(ws + O_WHH0);
  unsigned short* wih1p = (unsigned short*)(ws + O_WIH1);
  unsigned short* whh1p = (unsigned short*)(ws + O_WHH1);
  float* b0p = (float*)(ws + O_B0);
  float* b1p = (float*)(ws + O_B1);
  float* Wa  = (float*)(ws + O_WA);
  float* bc  = (float*)(ws + O_BC);
  float* em2 = (float*)(ws + O_EMB2);
  unsigned short* dp1t = (unsigned short*)(ws + O_DP1T);
  unsigned short* cp1t = (unsigned short*)(ws + O_CP1T);
  unsigned short* pc1t = (unsigned short*)(ws + O_PC1T);
  float* dp2t = (float*)(ws + O_DP2T);
  float* cp2t = (float*)(ws + O_CP2T);
  float* pc2t = (float*)(ws + O_PC2T);

  const int T0 = 32768, T1 = T0 + 65536, T2 = T1 + 65536, T3 = T2 + 65536,
            T4 = T3 + 512, T5 = T4 + 512, T6 = T5 + 2048, T7 = T6 + 64,
            T8 = T7 + 1024, T9 = T8 + 16384, T10 = T9 + 8192, T11 = T10 + 4096,
            T12 = T11 + 1024, T13 = T12 + 512, T14 = T13 + 128;

  for (int idx = blockIdx.x * 256 + threadIdx.x; idx < T14; idx += gridDim.x * 256) {
    if (idx < T3) {
      int u, Kin; const float* src; unsigned short* dst;
      if (idx < T0)      { u = idx;      Kin = 64;  src = w0ih; dst = wih0p; }
      else if (idx < T1) { u = idx - T0; Kin = 128; src = w0hh; dst = whh0p; }
      else if (idx < T2) { u = idx - T1; Kin = 128; src = w1ih; dst = wih1p; }
      else               { u = idx - T2; Kin = 128; src = w1hh; dst = whh1p; }
      int j = u & 7, l = (u >> 3) & 63, nt = (u >> 9) & 31, kt = u >> 14;
      int c = 16 * nt + (l & 15);
      int k = 32 * kt + 8 * (l >> 4) + j;
      dst[u] = f2b(src[orig_col(c) * Kin + k]);
    } else if (idx < T5) {
      int u = idx - T3;
      if (u < 512) b0p[u] = b0ih[orig_col(u)] + b0hh[orig_col(u)];
      else { int c = u - 512; b1p[c] = b1ih[orig_col(c)] + b1hh[orig_col(c)]; }
    } else if (idx < T6) {
      int u = idx - T5, f = u >> 5, kk = u & 31;
      float a = 0.f;
      for (int f2 = 0; f2 < 64; f2++) a += comb_w[f * 80 + f2] * de_w2[f2 * 32 + kk];
      Wa[u] = a;
    } else if (idx < T7) {
      int f = idx - T6;
      float a = comb_b[f];
      for (int f2 = 0; f2 < 64; f2++) a += comb_w[f * 80 + f2] * de_b2[f2];
      bc[f] = a;
    } else if (idx < T8) {
      int u = idx - T7, e = u >> 6, f = u & 63;
      float a = 0.f;
      for (int j = 0; j < 16; j++) a += embed[e * 16 + j] * comb_w[f * 80 + 64 + j];
      em2[u] = a;
    } else if (idx < T9)  { int u = idx - T8;  int dd = u >> 7, kx = u & 127; dp1t[u] = f2b(dp_w1[dd * 128 + (kx ^ ((dd & 15) << 3))]); }
    else if (idx < T10)   { int u = idx - T9;  int dd = u >> 7, kx = u & 127; cp1t[u] = f2b(cp_w1[dd * 128 + (kx ^ ((dd & 15) << 3))]); }
    else if (idx < T11)   { int u = idx - T10; int dd = u >> 7, kx = u & 127; pc1t[u] = f2b(pc_w1[dd * 128 + (kx ^ ((dd & 15) << 3))]); }
    else if (idx < T12)   { int u = idx - T11; int k = u >> 3, o = u & 7;   dp2t[u] = dp_w2[o * 128 + k]; }
    else if (idx < T13)   { int u = idx - T12; int k = u >> 3, o = u & 7;   cp2t[u] = cp_w2[o * 64 + k]; }
    else                  { int u = idx - T13; int k = u >> 2, o = u & 3;   pc2t[u] = pc_w2[o * 32 + k]; }
  }
}

// =============================== frontend ===============================
__global__ __launch_bounds__(256) void frontend_kernel(
    const float* __restrict__ x_feat, const int* __restrict__ acc_t,
    const float* __restrict__ de_w1, const float* __restrict__ de_b1,
    const char* __restrict__ ws, unsigned short* __restrict__ feats)
{
  __shared__ float sW1[256], sB1[32], sWa[2048], sBc[64], sE2T[1024];
  const float* Wa  = (const float*)(ws + O_WA);
  const float* bc  = (const float*)(ws + O_BC);
  const float* em2 = (const float*)(ws + O_EMB2);
  int tid = threadIdx.x;
  sW1[tid] = de_w1[tid];
  if (tid < 32) sB1[tid] = de_b1[tid];
  for (int i = tid; i < 2048; i += 256) sWa[i] = Wa[i];
  if (tid < 64) sBc[tid] = bc[tid];
  for (int i = tid; i < 1024; i += 256) sE2T[i] = em2[(i & 15) * 64 + (i >> 4)];
  __syncthreads();

  int g = blockIdx.x * 256 + tid;
  f4v x0 = ((const f4v*)(x_feat + (size_t)g * 8))[0];
  f4v x1 = ((const f4v*)(x_feat + (size_t)g * 8))[1];
  float xs[8];
#pragma unroll
  for (int i = 0; i < 4; i++) { xs[i] = x0[i]; xs[4 + i] = x1[i]; }
  int at = acc_t[g];

  float r1[32];
#pragma unroll
  for (int kk = 0; kk < 32; kk++) {
    float a = sB1[kk];
#pragma unroll
    for (int i = 0; i < 8; i++) a += xs[i] * sW1[kk * 8 + i];
    r1[kk] = fmaxf(a, 0.f);
  }
  unsigned short* dst = feats + (size_t)g * 64;
  for (int j8 = 0; j8 < 8; j8++) {
    s8v pack;
#pragma unroll
    for (int jj = 0; jj < 8; jj++) {
      int j = j8 * 8 + jj;
      float a = sBc[j] + sE2T[j * 16 + at];
      const f4v* wr = (const f4v*)(sWa + j * 32);
#pragma unroll
      for (int k4 = 0; k4 < 8; k4++) {
        f4v wv = wr[k4];
        a += r1[4 * k4 + 0] * wv[0] + r1[4 * k4 + 1] * wv[1] +
             r1[4 * k4 + 2] * wv[2] + r1[4 * k4 + 3] * wv[3];
      }
      pack[jj] = (short)f2b(a);
    }
    *(s8v*)(dst + j8 * 8) = pack;
  }
}

// =============================== heads (block-local epilogue) ===============================
DEV void heads_phase(int tid, int blk, char* pool,
                     const float* __restrict__ dp_b2, const float* __restrict__ cp_b2,
                     const float* __restrict__ pc_b2, float* __restrict__ out)
{
  const float* sh = (const float*)(pool + P_HF);
  const unsigned short* sw1 = (const unsigned short*)(pool + P_HW1);
  const float* sw2 = (const float*)(pool + P_HW2);
  const float* sb1 = (const float*)(pool + P_HB1);
  float* smid = (float*)(pool + P_HMID);
  float* spc = (float*)(pool + P_HPC);

  for (int i = tid; i < 7168; i += 512) {
    int row = i / 224, md = i - row * 224;
    const unsigned short* wr; int dd;
    if (md < 128)      { dd = md;       wr = sw1 + dd * 128; }
    else if (md < 192) { dd = md - 128; wr = sw1 + 16384 + dd * 128; }
    else               { dd = md - 192; wr = sw1 + 24576 + dd * 128; }
    float a = sb1[md];
    int s = (dd & 15) << 3;
    const float* hr = sh + row * 128;
#pragma unroll
    for (int kb = 0; kb < 16; kb++) {
      int k0 = (kb * 8) ^ s;
      s8v wv = *(const s8v*)(wr + kb * 8);
      f4v h0 = *(const f4v*)(hr + k0);
      f4v h1 = *(const f4v*)(hr + k0 + 4);
      a += h0[0] * b2f(wv[0]) + h0[1] * b2f(wv[1]) + h0[2] * b2f(wv[2]) + h0[3] * b2f(wv[3]) +
           h1[0] * b2f(wv[4]) + h1[1] * b2f(wv[5]) + h1[2] * b2f(wv[6]) + h1[3] * b2f(wv[7]);
    }
    smid[i] = fmaxf(a, 0.f);
  }
  __syncthreads();

  for (int i = tid; i < 640; i += 512) {
    int row = i / 20, o = i - row * 20;
    if (o < 8) {
      float a = dp_b2[o];
      for (int k = 0; k < 128; k++) a += smid[row * 224 + k] * sw2[k * 8 + o];
      out[(size_t)(blk * 32 + row) * 20 + o] = a * 1e6f;
    } else if (o < 16) {
      int oo = o - 8; float a = cp_b2[oo];
      for (int k = 0; k < 64; k++) a += smid[row * 224 + 128 + k] * sw2[1024 + k * 8 + oo];
      out[(size_t)(blk * 32 + row) * 20 + o] = __builtin_amdgcn_rcpf(1.f + __expf(-a));
    } else {
      int oo = o - 16; float a = pc_b2[oo];
      for (int k = 0; k < 32; k++) a += smid[row * 224 + 192 + k] * sw2[1536 + k * 4 + oo];
      spc[row * 4 + oo] = a;
    }
  }
  __syncthreads();

  if (tid < 32) {
    int row = tid;
    float v0 = spc[row * 4], v1 = spc[row * 4 + 1], v2 = spc[row * 4 + 2], v3 = spc[row * 4 + 3];
    float m = fmaxf(fmaxf(v0, v1), fmaxf(v2, v3));
    float e0 = __expf(v0 - m), e1 = __expf(v1 - m), e2 = __expf(v2 - m), e3 = __expf(v3 - m);
    float rs = __builtin_amdgcn_rcpf(e0 + e1 + e2 + e3);
    size_t base = (size_t)(blk * 32 + row) * 20 + 16;
    out[base] = e0 * rs; out[base + 1] = e1 * rs; out[base + 2] = e2 * rs; out[base + 3] = e3 * rs;
  }
}

// =============================== main LSTM ===============================
template <int PASS>
DEV void run_pass(int tid, int blk,
                  const unsigned short* __restrict__ whhp,
                  const unsigned short* __restrict__ wihp,
                  const float* __restrict__ bp,
                  const unsigned short* __restrict__ inglob,
                  unsigned short* __restrict__ y0buf,
                  char* pool, unsigned ctrbase)
{
  constexpr int NKT = PASS ? 4 : 2;
  constexpr int STEPB = PASS ? 8192 : 128;
  const int w = tid >> 6, l = tid & 63, l15 = l & 15, lhi = l >> 4;
  const int d = 16 * w + l15;
  const char* gb = (const char*)inglob;
  unsigned* ctr = (unsigned*)(pool + P_CTR);

  // stage whh kt0..2 into LDS (96KB linear copy of pre-packed frags)
  {
    const s8v* src = (const s8v*)whhp;
    s8v* dst = (s8v*)(pool + P_WLDS);
#pragma unroll
    for (int i = 0; i < 12; i++) dst[tid + i * 512] = src[tid + i * 512];
  }
  // zero h buffer 0
  { s8v z = {0,0,0,0,0,0,0,0}; *(s8v*)((unsigned short*)(pool + P_H0) + tid * 8) = z; }

  // per-lane global A pointers (t=0)
  const char *pe0, *pe1;
  {
    int row0 = l15, row1 = 16 + l15;
    if constexpr (PASS == 0) {
      pe0 = gb + (size_t)(blk * 32 + row0) * 4096 + lhi * 16;
      pe1 = gb + (size_t)(blk * 32 + row1) * 4096 + lhi * 16;
    } else {
      pe0 = gb + (size_t)blk * 262144 + row0 * 256 + lhi * 16;
      pe1 = gb + (size_t)blk * 262144 + row1 * 256 + lhi * 16;
    }
  }

  // weights -> registers: wih all kt; whh kt3 only
  s8v wf[NKT][4], bq[4];
#pragma unroll
  for (int kt = 0; kt < NKT; kt++)
#pragma unroll
    for (int gg = 0; gg < 4; gg++)
      wf[kt][gg] = *(const s8v*)(wihp + ((size_t)(kt * 32 + 4 * w + gg) * 64 + l) * 8);
#pragma unroll
  for (int gg = 0; gg < 4; gg++)
    bq[gg] = *(const s8v*)(whhp + ((size_t)(96 + 4 * w + gg) * 64 + l) * 8);

  const float nbi = -bp[64 * w + l15],        nbf = -bp[64 * w + 16 + l15],
              bg2 = 2.f * bp[64 * w + 32 + l15], nbo = -bp[64 * w + 48 + l15];

  // invariant addresses
  int hra[2][4], hwoff[2][4];
#pragma unroll
  for (int mt = 0; mt < 2; mt++)
#pragma unroll
    for (int kt = 0; kt < 4; kt++) {
      int row = 16 * mt + l15;
      hra[mt][kt] = row * 256 + ((kt * 64 + lhi * 16) ^ ((row & 7) << 4));
    }
#pragma unroll
  for (int mt = 0; mt < 2; mt++)
#pragma unroll
    for (int r = 0; r < 4; r++) {
      int row = 16 * mt + 4 * lhi + r;
      hwoff[mt][r] = row * 256 + ((d * 2) ^ ((row & 7) << 4));
    }
  const char* wb = pool + P_WLDS + w * 4096 + l * 16;  // whh kt0..2 frag base

  const int yldsb = (tid >> 4) * 256 + (tid & 15) * 16;
  unsigned short* py0 = y0buf ? (y0buf + (size_t)blk * 131072 + (tid >> 4) * 128 +
                                 (((tid & 15) ^ ((tid >> 4) & 7)) * 8))
                              : nullptr;

  float cst[2][4] = {{0,0,0,0},{0,0,0,0}};
  float hv[2][4];
  const f4v z4 = {0.f, 0.f, 0.f, 0.f};

  // prologue: load A(0)
  s8v AA[2][NKT];
#pragma unroll
  for (int kt = 0; kt < NKT; kt++) {
    AA[0][kt] = *(const s8v*)(pe0 + kt * 64);
    AA[1][kt] = *(const s8v*)(pe1 + kt * 64);
  }
  pe0 += STEPB; pe1 += STEPB;

  __syncthreads();  // publish WLDS + H0-zero + ctr

  f4v acc[2][4];
  // input MFMA t=0
#pragma unroll
  for (int mt = 0; mt < 2; mt++)
#pragma unroll
    for (int gg = 0; gg < 4; gg++)
      acc[mt][gg] = __builtin_amdgcn_mfma_f32_16x16x32_bf16(AA[mt][0], wf[0][gg], z4, 0, 0, 0);
#pragma unroll
  for (int kt = 1; kt < NKT; kt++)
#pragma unroll
    for (int mt = 0; mt < 2; mt++)
#pragma unroll
      for (int gg = 0; gg < 4; gg++)
        acc[mt][gg] = __builtin_amdgcn_mfma_f32_16x16x32_bf16(AA[mt][kt], wf[kt][gg], acc[mt][gg], 0, 0, 0);
  // prefetch A(1)
#pragma unroll
  for (int kt = 0; kt < NKT; kt++) {
    AA[0][kt] = *(const s8v*)(pe0 + kt * 64);
    AA[1][kt] = *(const s8v*)(pe1 + kt * 64);
  }
  pe0 += STEPB; pe1 += STEPB;

#define POINTWISE(T)                                                            \
  _Pragma("unroll") for (int mt = 0; mt < 2; mt++)                              \
    _Pragma("unroll") for (int r = 0; r < 4; r++) {                             \
      float xi = acc[mt][0][r], xf = acc[mt][1][r],                             \
            xg = acc[mt][2][r], xo = acc[mt][3][r];                             \
      float iv = __builtin_amdgcn_rcpf(1.f + __expf(fmaf(xi, -1.f, nbi)));      \
      float fv = __builtin_amdgcn_rcpf(1.f + __expf(fmaf(xf, -1.f, nbf)));      \
      float ov = __builtin_amdgcn_rcpf(1.f + __expf(fmaf(xo, -1.f, nbo)));      \
      float eg = __expf(fmaf(xg, 2.f, bg2));                                    \
      float gv = fmaf(-2.f, __builtin_amdgcn_rcpf(eg + 1.f), 1.f);              \
      float cv = fmaf(fv, cst[mt][r], iv * gv);                                 \
      cst[mt][r] = cv;                                                          \
      float ec = __expf(2.f * cv);                                              \
      float th = fmaf(-2.f, __builtin_amdgcn_rcpf(ec + 1.f), 1.f);              \
      float hvv = ov * th;                                                      \
      hv[mt][r] = hvv;                                                          \
      if (PASS == 1 && (T) == 31) {                                             \
        int row = 16 * mt + 4 * lhi + r;                                        \
        ((float*)(pool + P_HF))[row * 128 + d] = hvv;                           \
      }                                                                         \
    }

  POINTWISE(0)  // h(0)

  for (int tn = 1; tn < 32; ++tn) {
    char* hb = pool + ((tn & 1) ? P_H0 : P_H1);  // buf[(tn-1)&1]
    // 1. publish h(tn-1)
#pragma unroll
    for (int mt = 0; mt < 2; mt++)
#pragma unroll
      for (int r = 0; r < 4; r++)
        *(unsigned short*)(hb + hwoff[mt][r]) = f2b(hv[mt][r]);
    asm volatile("s_waitcnt lgkmcnt(0)" ::: "memory");
    if (l == 0) atomicAdd(ctr, 1u);
    // 2. independent work: input MFMA for t=tn
#pragma unroll
    for (int mt = 0; mt < 2; mt++)
#pragma unroll
      for (int gg = 0; gg < 4; gg++)
        acc[mt][gg] = __builtin_amdgcn_mfma_f32_16x16x32_bf16(AA[mt][0], wf[0][gg], z4, 0, 0, 0);
#pragma unroll
    for (int kt = 1; kt < NKT; kt++)
#pragma unroll
      for (int mt = 0; mt < 2; mt++)
#pragma unroll
        for (int gg = 0; gg < 4; gg++)
          acc[mt][gg] = __builtin_amdgcn_mfma_f32_16x16x32_bf16(AA[mt][kt], wf[kt][gg], acc[mt][gg], 0, 0, 0);
    // 3. prefetch A(tn+1)
    if (tn < 31) {
#pragma unroll
      for (int kt = 0; kt < NKT; kt++) {
        AA[0][kt] = *(const s8v*)(pe0 + kt * 64);
        AA[1][kt] = *(const s8v*)(pe1 + kt * 64);
      }
      pe0 += STEPB; pe1 += STEPB;
    }
    // 4. wait for all h(tn-1)
    {
      unsigned tgt = ctrbase + 8u * (unsigned)tn;
      while (*(volatile unsigned*)ctr < tgt) __builtin_amdgcn_s_sleep(2);
      asm volatile("" ::: "memory");
    }
    // 5. recurrent MFMA on h(tn-1)
#pragma unroll
    for (int kt = 0; kt < 3; kt++) {
      s8v bfr[4];
#pragma unroll
      for (int gg = 0; gg < 4; gg++)
        bfr[gg] = *(const s8v*)(wb + kt * 32768 + gg * 1024);
#pragma unroll
      for (int mt = 0; mt < 2; mt++) {
        s8v ha = *(const s8v*)(hb + hra[mt][kt]);
#pragma unroll
        for (int gg = 0; gg < 4; gg++)
          acc[mt][gg] = __builtin_amdgcn_mfma_f32_16x16x32_bf16(ha, bfr[gg], acc[mt][gg], 0, 0, 0);
      }
    }
#pragma unroll
    for (int mt = 0; mt < 2; mt++) {
      s8v ha = *(const s8v*)(hb + hra[mt][3]);
#pragma unroll
      for (int gg = 0; gg < 4; gg++)
        acc[mt][gg] = __builtin_amdgcn_mfma_f32_16x16x32_bf16(ha, bq[gg], acc[mt][gg], 0, 0, 0);
    }
    // 6. y0 out for t=tn-1 (pass0)
    if (PASS == 0) {
      s8v hv8 = *(const s8v*)(hb + yldsb);
      *(s8v*)(py0 + (size_t)(tn - 1) * 4096) = hv8;
    }
    // 7. pointwise -> h(tn)
    POINTWISE(tn)
  }
#undef POINTWISE

  if constexpr (PASS == 0) {  // publish + write y0 for h(31) (parity 1)
    char* hb = pool + P_H1;
#pragma unroll
    for (int mt = 0; mt < 2; mt++)
#pragma unroll
      for (int r = 0; r < 4; r++)
        *(unsigned short*)(hb + hwoff[mt][r]) = f2b(hv[mt][r]);
    asm volatile("s_waitcnt lgkmcnt(0)" ::: "memory");
    if (l == 0) atomicAdd(ctr, 1u);
    unsigned tgt = ctrbase + 256u;
    while (*(volatile unsigned*)ctr < tgt) __builtin_amdgcn_s_sleep(2);
    asm volatile("" ::: "memory");
    s8v hv8 = *(const s8v*)(hb + yldsb);
    *(s8v*)(py0 + (size_t)31 * 4096) = hv8;
  }
}

__global__ __attribute__((amdgpu_waves_per_eu(2, 2))) __launch_bounds__(512)
void lstm_main(
    const char* __restrict__ ws_c, char* __restrict__ ws,
    const float* __restrict__ dp_b1, const float* __restrict__ dp_b2,
    const float* __restrict__ cp_b1, const float* __restrict__ cp_b2,
    const float* __restrict__ pc_b1, const float* __restrict__ pc_b2,
    float* __restrict__ out)
{
  __shared__ __align__(16) char pool[P_TOT];
  int tid = threadIdx.x, blk = blockIdx.x;
  if (tid == 0) *(unsigned*)(pool + P_CTR) = 0u;

  run_pass<0>(tid, blk,
              (const unsigned short*)(ws_c + O_WHH0), (const unsigned short*)(ws_c + O_WIH0),
              (const float*)(ws_c + O_B0),
              (const unsigned short*)(ws_c + O_FEATS),
              (unsigned short*)(ws + O_Y0), pool, 0u);
  __syncthreads();
  run_pass<1>(tid, blk,
              (const unsigned short*)(ws_c + O_WHH1), (const unsigned short*)(ws_c + O_WIH1),
              (const float*)(ws_c + O_B1),
              (const unsigned short*)(ws + O_Y0),
              nullptr, pool, 256u);
  __syncthreads();

  // stage head weights into aliased LDS (pass buffers now dead)
  {
    const s8v* w1s = (const s8v*)(ws_c + O_DP1T);
    s8v* dw = (s8v*)(pool + P_HW1);
    for (int i = tid; i < 3584; i += 512) dw[i] = w1s[i];
    const float* w2s = (const float*)(ws_c + O_DP2T);
    float* d2 = (float*)(pool + P_HW2);
    for (int i = tid; i < 1664; i += 512) d2[i] = w2s[i];
    float* b1 = (float*)(pool + P_HB1);
    if (tid < 128) b1[tid] = dp_b1[tid];
    else if (tid < 192) b1[tid] = cp_b1[tid - 128];
    else if (tid < 224) b1[tid] = pc_b1[tid - 192];
  }
  __syncthreads();
  heads_phase(tid, blk, pool, dp_b2, cp_b2, pc_b2, out);
}

// =============================== launch ===============================
extern "C" void kernel_launch(void* const* d_in, const int* in_sizes, int n_in,
                              void* d_out, int out_size, void* d_ws, size_t ws_size,
                              hipStream_t stream) {
  const float* x_feat = (const float*)d_in[0];
  const int*   acc_t  = (const int*)d_in[1];
  const float* de_w1 = (const float*)d_in[2],  *de_b1 = (const float*)d_in[3];
  const float* de_w2 = (const float*)d_in[4],  *de_b2 = (const float*)d_in[5];
  const float* embed = (const float*)d_in[6];
  const float* comb_w = (const float*)d_in[7], *comb_b = (const float*)d_in[8];
  const float* w0ih = (const float*)d_in[9],  *w0hh = (const float*)d_in[10];
  const float* b0ih = (const float*)d_in[11], *b0hh = (const float*)d_in[12];
  const float* w1ih = (const float*)d_in[13], *w1hh = (const float*)d_in[14];
  const float* b1ih = (const float*)d_in[15], *b1hh = (const float*)d_in[16];
  const float* dp_w1 = (const float*)d_in[17], *dp_b1 = (const float*)d_in[18];
  const float* dp_w2 = (const float*)d_in[19], *dp_b2 = (const float*)d_in[20];
  const float* cp_w1 = (const float*)d_in[21], *cp_b1 = (const float*)d_in[22];
  const float* cp_w2 = (const float*)d_in[23], *cp_b2 = (const float*)d_in[24];
  const float* pc_w1 = (const float*)d_in[25], *pc_b1 = (const float*)d_in[26];
  const float* pc_w2 = (const float*)d_in[27], *pc_b2 = (const float*)d_in[28];
  char* ws = (char*)d_ws;

  prep_kernel<<<256, 256, 0, stream>>>(
      de_w1, de_b1, de_w2, de_b2, embed, comb_w, comb_b,
      w0ih, w0hh, b0ih, b0hh, w1ih, w1hh, b1ih, b1hh,
      dp_w1, dp_w2, cp_w1, cp_w2, pc_w1, pc_w2, ws);

  frontend_kernel<<<1024, 256, 0, stream>>>(
      x_feat, acc_t, de_w1, de_b1, ws, (unsigned short*)(ws + O_FEATS));

  lstm_main<<<256, 512, 0, stream>>>(
      ws, ws, dp_b1, dp_b2, cp_b1, cp_b2, pc_b1, pc_b2, (float*)d_out);
}